// Round 6
// baseline (316.953 us; speedup 1.0000x reference)
//
#include <hip/hip_runtime.h>
#include <math.h>

#define BATCH 64
#define NV 1024
#define NL 512
#define DIM 512
#define TMM 256
#define TNN 128
#define BK 32
#define NKT (DIM / BK)   // 16 K-iterations

typedef __bf16 bf16x8 __attribute__((ext_vector_type(8)));
typedef __bf16 bf16x4 __attribute__((ext_vector_type(4)));
typedef float f32x4 __attribute__((ext_vector_type(4)));

// =====================================================================
// Fused kernel: fp32 load -> (norms, bf16 convert) -> LDS -> MFMA GEMM
// -> distance epilogue -> row/col min partials.
// grid = 1024 (XCD-chunked to (b, mt, nt)), block = 512 (8 waves, 4x2
// of 64x64 wave tiles over a 256x128 output tile).
// LDS trimmed under 54613 B (epilogue scratch aliased onto AsU) so
// 3 blocks/CU are co-resident; launch_bounds(512,6) caps VGPR at 84.
// =====================================================================
__global__ __launch_bounds__(512, 6) void fused_distmin_kernel(
    const float* __restrict__ video, const float* __restrict__ lang,
    float* __restrict__ rowpart, float* __restrict__ colpart) {
    // Octet-major LDS: slab o in [0,4) holds k = [o*8, o*8+8) for all rows,
    // 16B per (o,row) entry. b128 reads and b64 writes are bank-even.
    __shared__ __align__(16) ushort AsU[2][4][TMM][8];  // 32 KB
    __shared__ __align__(16) ushort BsU[2][4][TNN][8];  // 16 KB
    __shared__ float anrm[TMM], bnrm[TNN];              // 1.5 KB
    // Epilogue scratch aliased onto AsU (only touched after the last
    // MFMA read of AsU, past a __syncthreads): saves 4 KB -> 3 blocks/CU.
    float* rowred = (float*)AsU;             // [2][TMM] = 2 KB
    float* colred = (float*)AsU + 2 * TMM;   // [4][TNN] = 2 KB

    // XCD-aware chunked swizzle: nwg = 1024 = 8 XCD * 128; each XCD gets
    // 8 complete batches; 16 consecutive wg share one batch (L2 locality).
    const int wg = ((blockIdx.x & 7) << 7) | (blockIdx.x >> 3);
    const int b = wg >> 4;          // 64 batches
    const int mt = (wg >> 2) & 3;   // 4 video row-blocks of 256
    const int nt = wg & 3;          // 4 lang col-blocks of 128

    const int tid = threadIdx.x;
    const int lane = tid & 63;
    const int w = tid >> 6;         // 0..7
    const int wrow = w >> 1;        // 0..3
    const int wcol = w & 1;         // 0..1
    const int lr = lane & 15;
    const int g = lane >> 4;        // k-octet for fragment reads

    // staging geometry: srow in [0,64), skq = k-quad in [0,8)
    const int srow = tid >> 3;
    const int skq = tid & 7;
    const int o_sl = skq >> 1;      // LDS slab
    const int half = skq & 1;       // 8B half of the 16B entry

    const float* Ath = video + ((size_t)b * NV + (size_t)mt * TMM + srow) * DIM + skq * 4;
    const float* Bth = lang + ((size_t)b * NL + (size_t)nt * TNN + srow) * DIM + skq * 4;

    float nA[4] = {0.f, 0.f, 0.f, 0.f};   // rows srow + 64t
    float nB[2] = {0.f, 0.f};             // rows srow, srow+64

    f32x4 acc[4][4];
#pragma unroll
    for (int i = 0; i < 4; i++)
#pragma unroll
        for (int j = 0; j < 4; j++) acc[i][j] = (f32x4){0.f, 0.f, 0.f, 0.f};

    float4 va[4], vb[2];

    auto load_chunk = [&](int k0) {
#pragma unroll
        for (int t = 0; t < 4; ++t)
            va[t] = *(const float4*)(Ath + (size_t)t * 64 * DIM + k0);
#pragma unroll
        for (int t = 0; t < 2; ++t)
            vb[t] = *(const float4*)(Bth + (size_t)t * 64 * DIM + k0);
    };
    auto write_chunk = [&](int buf) {
#pragma unroll
        for (int t = 0; t < 4; ++t) {
            float4 v = va[t];
            nA[t] += v.x * v.x + v.y * v.y + v.z * v.z + v.w * v.w;
            bf16x4 p = {(__bf16)v.x, (__bf16)v.y, (__bf16)v.z, (__bf16)v.w};
            *(bf16x4*)&AsU[buf][o_sl][srow + 64 * t][half * 4] = p;
        }
#pragma unroll
        for (int t = 0; t < 2; ++t) {
            float4 u = vb[t];
            nB[t] += u.x * u.x + u.y * u.y + u.z * u.z + u.w * u.w;
            bf16x4 q = {(__bf16)u.x, (__bf16)u.y, (__bf16)u.z, (__bf16)u.w};
            *(bf16x4*)&BsU[buf][o_sl][srow + 64 * t][half * 4] = q;
        }
    };

    // prologue: stage k-tile 0 into buf 0
    load_chunk(0);
    write_chunk(0);
    __syncthreads();

    for (int kt = 0; kt < NKT; ++kt) {
        const int cur = kt & 1;
        const bool more = (kt + 1) < NKT;
        if (more) load_chunk((kt + 1) * BK);   // next-tile loads issued early

        bf16x8 av[4], bv[4];
#pragma unroll
        for (int fr = 0; fr < 4; ++fr)
            av[fr] = *(const bf16x8*)&AsU[cur][g][wrow * 64 + fr * 16 + lr][0];
#pragma unroll
        for (int fc = 0; fc < 4; ++fc)
            bv[fc] = *(const bf16x8*)&BsU[cur][g][wcol * 64 + fc * 16 + lr][0];
#pragma unroll
        for (int fr = 0; fr < 4; ++fr)
#pragma unroll
            for (int fc = 0; fc < 4; ++fc)
                acc[fr][fc] = __builtin_amdgcn_mfma_f32_16x16x32_bf16(
                    av[fr], bv[fc], acc[fr][fc], 0, 0, 0);

        if (more) write_chunk(cur ^ 1);        // cvt + norm-fma + ds_write after MFMA
        __syncthreads();
    }

    // ---- norms: reduce partials across the 8 threads sharing each row ----
#pragma unroll
    for (int s = 1; s < 8; s <<= 1) {
#pragma unroll
        for (int t = 0; t < 4; ++t) nA[t] += __shfl_xor(nA[t], s);
#pragma unroll
        for (int t = 0; t < 2; ++t) nB[t] += __shfl_xor(nB[t], s);
    }
    if ((tid & 7) == 0) {
#pragma unroll
        for (int t = 0; t < 4; ++t) anrm[srow + 64 * t] = nA[t];
#pragma unroll
        for (int t = 0; t < 2; ++t) bnrm[srow + 64 * t] = nB[t];
    }
    __syncthreads();   // after this barrier AsU is dead -> rowred/colred alias OK

    // ---- epilogue: d = |v|^2 - 2 dot + |l|^2, row/col mins ----
    const int rgrp = (lane >> 4) * 4;
    float anorm[4][4];
#pragma unroll
    for (int fr = 0; fr < 4; ++fr)
#pragma unroll
        for (int r = 0; r < 4; ++r)
            anorm[fr][r] = anrm[wrow * 64 + fr * 16 + rgrp + r];
    float bnorm[4];
#pragma unroll
    for (int fc = 0; fc < 4; ++fc)
        bnorm[fc] = bnrm[wcol * 64 + fc * 16 + lr];

    float rmin[4][4];
    float cmin[4];
#pragma unroll
    for (int fr = 0; fr < 4; ++fr)
#pragma unroll
        for (int r = 0; r < 4; ++r) rmin[fr][r] = INFINITY;
#pragma unroll
    for (int fc = 0; fc < 4; ++fc) cmin[fc] = INFINITY;

#pragma unroll
    for (int fr = 0; fr < 4; ++fr)
#pragma unroll
        for (int fc = 0; fc < 4; ++fc)
#pragma unroll
            for (int r = 0; r < 4; ++r) {
                float d = anorm[fr][r] - 2.0f * acc[fr][fc][r] + bnorm[fc];
                rmin[fr][r] = fminf(rmin[fr][r], d);
                cmin[fc] = fminf(cmin[fc], d);
            }

#pragma unroll
    for (int fr = 0; fr < 4; ++fr)
#pragma unroll
        for (int r = 0; r < 4; ++r) {
#pragma unroll
            for (int off = 1; off < 16; off <<= 1)
                rmin[fr][r] = fminf(rmin[fr][r], __shfl_xor(rmin[fr][r], off));
        }
#pragma unroll
    for (int fc = 0; fc < 4; ++fc) {
#pragma unroll
        for (int off = 16; off < 64; off <<= 1)
            cmin[fc] = fminf(cmin[fc], __shfl_xor(cmin[fc], off));
    }

    if ((lane & 15) == 0) {
#pragma unroll
        for (int fr = 0; fr < 4; ++fr)
#pragma unroll
            for (int r = 0; r < 4; ++r)
                rowred[wcol * TMM + wrow * 64 + fr * 16 + rgrp + r] = rmin[fr][r];
    }
    if (lane < 16) {
#pragma unroll
        for (int fc = 0; fc < 4; ++fc)
            colred[wrow * TNN + wcol * 64 + fc * 16 + lane] = cmin[fc];
    }
    __syncthreads();
    if (tid < TMM) {
        rowpart[((size_t)(b * 4 + nt)) * NV + mt * TMM + tid] =
            fminf(rowred[tid], rowred[TMM + tid]);
    } else if (tid < TMM + TNN) {
        int c2 = tid - TMM;
        colpart[((size_t)(b * 4 + mt)) * NL + nt * TNN + c2] =
            fminf(fminf(colred[0 * TNN + c2], colred[1 * TNN + c2]),
                  fminf(colred[2 * TNN + c2], colred[3 * TNN + c2]));
    }
}

// ---------------- final reduce ----------------------------------------------
__global__ __launch_bounds__(256) void reduce2_kernel(
    const float* __restrict__ rowpart, const float* __restrict__ colpart,
    float* __restrict__ out) {
    int b = blockIdx.x;
    int tid = threadIdx.x;
    float s = 0.0f;
    for (int r = tid; r < NV; r += 256) {
        float m = INFINITY;
#pragma unroll
        for (int nt = 0; nt < 4; nt++)
            m = fminf(m, rowpart[((size_t)(b * 4 + nt)) * NV + r]);
        s += m * (1.0f / NV);
    }
    for (int c = tid; c < NL; c += 256) {
        float m = INFINITY;
#pragma unroll
        for (int mt = 0; mt < 4; mt++)
            m = fminf(m, colpart[((size_t)(b * 4 + mt)) * NL + c]);
        s += m * (1.0f / NL);
    }
    __shared__ float red[4];
#pragma unroll
    for (int off = 32; off > 0; off >>= 1) s += __shfl_down(s, off);
    if ((tid & 63) == 0) red[tid >> 6] = s;
    __syncthreads();
    if (tid == 0) out[b] = red[0] + red[1] + red[2] + red[3];
}

// ============================================================================
extern "C" void kernel_launch(void* const* d_in, const int* in_sizes, int n_in,
                              void* d_out, int out_size, void* d_ws, size_t ws_size,
                              hipStream_t stream) {
    const float* video = (const float*)d_in[0];  // [64,1024,512] fp32
    const float* lang = (const float*)d_in[1];   // [64,512,512] fp32
    float* out = (float*)d_out;                  // [64]

    float* rowpart = (float*)d_ws;                      // 64*4*1024 floats (1 MB)
    float* colpart = rowpart + (size_t)BATCH * 4 * NV;  // 64*4*512 floats (0.5 MB)

    fused_distmin_kernel<<<dim3(1024), 512, 0, stream>>>(video, lang, rowpart, colpart);
    reduce2_kernel<<<BATCH, 256, 0, stream>>>(rowpart, colpart, out);
}

// Round 7
// 69.595 us; speedup vs baseline: 4.5543x; 4.5543x over previous
//
#include <hip/hip_runtime.h>
#include <math.h>

#define BATCH 64
#define NV 1024
#define NL 512
#define DIM 512
#define TMM 256
#define TNN 128
#define BK 32
#define NKT (DIM / BK)   // 16 K-iterations

typedef __bf16 bf16x8 __attribute__((ext_vector_type(8)));
typedef __bf16 bf16x4 __attribute__((ext_vector_type(4)));
typedef float f32x4 __attribute__((ext_vector_type(4)));

// =====================================================================
// Fused kernel: fp32 load -> (norms, bf16 convert) -> LDS -> MFMA GEMM
// -> distance epilogue -> row/col min partials.
// grid = 1024 (XCD-chunked to (b, mt, nt)), block = 512 (8 waves, 4x2
// of 64x64 wave tiles over a 256x128 output tile).
// LDS 50688 B (epilogue scratch aliased onto AsU) -> 3 blocks/CU.
// launch_bounds(512,2): do NOT tighten — R6 showed a tighter min-waves
// hint caps VGPR below the 64 accumulator registers and spills (650 MB
// scratch traffic, 4.5x regression). Natural alloc is 64 VGPR -> 24
// waves/CU fits the 512-VGPR/SIMD pool without any hint.
// =====================================================================
__global__ __launch_bounds__(512, 2) void fused_distmin_kernel(
    const float* __restrict__ video, const float* __restrict__ lang,
    float* __restrict__ rowpart, float* __restrict__ colpart) {
    // Octet-major LDS: slab o in [0,4) holds k = [o*8, o*8+8) for all rows,
    // 16B per (o,row) entry. b128 reads and b64 writes are bank-even.
    __shared__ __align__(16) ushort AsU[2][4][TMM][8];  // 32 KB
    __shared__ __align__(16) ushort BsU[2][4][TNN][8];  // 16 KB
    __shared__ float anrm[TMM], bnrm[TNN];              // 1.5 KB
    // Epilogue scratch aliased onto AsU (only touched after the last
    // MFMA read of AsU, past a __syncthreads): saves 4 KB -> 3 blocks/CU.
    float* rowred = (float*)AsU;             // [2][TMM] = 2 KB
    float* colred = (float*)AsU + 2 * TMM;   // [4][TNN] = 2 KB

    // XCD-aware chunked swizzle: nwg = 1024 = 8 XCD * 128; each XCD gets
    // 8 complete batches; 16 consecutive wg share one batch (L2 locality).
    const int wg = ((blockIdx.x & 7) << 7) | (blockIdx.x >> 3);
    const int b = wg >> 4;          // 64 batches
    const int mt = (wg >> 2) & 3;   // 4 video row-blocks of 256
    const int nt = wg & 3;          // 4 lang col-blocks of 128

    const int tid = threadIdx.x;
    const int lane = tid & 63;
    const int w = tid >> 6;         // 0..7
    const int wrow = w >> 1;        // 0..3
    const int wcol = w & 1;         // 0..1
    const int lr = lane & 15;
    const int g = lane >> 4;        // k-octet for fragment reads

    // staging geometry: srow in [0,64), skq = k-quad in [0,8)
    const int srow = tid >> 3;
    const int skq = tid & 7;
    const int o_sl = skq >> 1;      // LDS slab
    const int half = skq & 1;       // 8B half of the 16B entry

    const float* Ath = video + ((size_t)b * NV + (size_t)mt * TMM + srow) * DIM + skq * 4;
    const float* Bth = lang + ((size_t)b * NL + (size_t)nt * TNN + srow) * DIM + skq * 4;

    float nA[4] = {0.f, 0.f, 0.f, 0.f};   // rows srow + 64t
    float nB[2] = {0.f, 0.f};             // rows srow, srow+64

    f32x4 acc[4][4];
#pragma unroll
    for (int i = 0; i < 4; i++)
#pragma unroll
        for (int j = 0; j < 4; j++) acc[i][j] = (f32x4){0.f, 0.f, 0.f, 0.f};

    float4 va[4], vb[2];

    auto load_chunk = [&](int k0) {
#pragma unroll
        for (int t = 0; t < 4; ++t)
            va[t] = *(const float4*)(Ath + (size_t)t * 64 * DIM + k0);
#pragma unroll
        for (int t = 0; t < 2; ++t)
            vb[t] = *(const float4*)(Bth + (size_t)t * 64 * DIM + k0);
    };
    auto write_chunk = [&](int buf) {
#pragma unroll
        for (int t = 0; t < 4; ++t) {
            float4 v = va[t];
            nA[t] += v.x * v.x + v.y * v.y + v.z * v.z + v.w * v.w;
            bf16x4 p = {(__bf16)v.x, (__bf16)v.y, (__bf16)v.z, (__bf16)v.w};
            *(bf16x4*)&AsU[buf][o_sl][srow + 64 * t][half * 4] = p;
        }
#pragma unroll
        for (int t = 0; t < 2; ++t) {
            float4 u = vb[t];
            nB[t] += u.x * u.x + u.y * u.y + u.z * u.z + u.w * u.w;
            bf16x4 q = {(__bf16)u.x, (__bf16)u.y, (__bf16)u.z, (__bf16)u.w};
            *(bf16x4*)&BsU[buf][o_sl][srow + 64 * t][half * 4] = q;
        }
    };

    // prologue: stage k-tile 0 into buf 0
    load_chunk(0);
    write_chunk(0);
    __syncthreads();

    for (int kt = 0; kt < NKT; ++kt) {
        const int cur = kt & 1;
        const bool more = (kt + 1) < NKT;
        if (more) load_chunk((kt + 1) * BK);   // next-tile loads issued early

        bf16x8 av[4], bv[4];
#pragma unroll
        for (int fr = 0; fr < 4; ++fr)
            av[fr] = *(const bf16x8*)&AsU[cur][g][wrow * 64 + fr * 16 + lr][0];
#pragma unroll
        for (int fc = 0; fc < 4; ++fc)
            bv[fc] = *(const bf16x8*)&BsU[cur][g][wcol * 64 + fc * 16 + lr][0];
#pragma unroll
        for (int fr = 0; fr < 4; ++fr)
#pragma unroll
            for (int fc = 0; fc < 4; ++fc)
                acc[fr][fc] = __builtin_amdgcn_mfma_f32_16x16x32_bf16(
                    av[fr], bv[fc], acc[fr][fc], 0, 0, 0);

        if (more) write_chunk(cur ^ 1);        // cvt + norm-fma + ds_write after MFMA
        __syncthreads();
    }

    // ---- norms: reduce partials across the 8 threads sharing each row ----
#pragma unroll
    for (int s = 1; s < 8; s <<= 1) {
#pragma unroll
        for (int t = 0; t < 4; ++t) nA[t] += __shfl_xor(nA[t], s);
#pragma unroll
        for (int t = 0; t < 2; ++t) nB[t] += __shfl_xor(nB[t], s);
    }
    if ((tid & 7) == 0) {
#pragma unroll
        for (int t = 0; t < 4; ++t) anrm[srow + 64 * t] = nA[t];
#pragma unroll
        for (int t = 0; t < 2; ++t) bnrm[srow + 64 * t] = nB[t];
    }
    __syncthreads();   // after this barrier AsU is dead -> rowred/colred alias OK

    // ---- epilogue: d = |v|^2 - 2 dot + |l|^2, row/col mins ----
    const int rgrp = (lane >> 4) * 4;
    float anorm[4][4];
#pragma unroll
    for (int fr = 0; fr < 4; ++fr)
#pragma unroll
        for (int r = 0; r < 4; ++r)
            anorm[fr][r] = anrm[wrow * 64 + fr * 16 + rgrp + r];
    float bnorm[4];
#pragma unroll
    for (int fc = 0; fc < 4; ++fc)
        bnorm[fc] = bnrm[wcol * 64 + fc * 16 + lr];

    float rmin[4][4];
    float cmin[4];
#pragma unroll
    for (int fr = 0; fr < 4; ++fr)
#pragma unroll
        for (int r = 0; r < 4; ++r) rmin[fr][r] = INFINITY;
#pragma unroll
    for (int fc = 0; fc < 4; ++fc) cmin[fc] = INFINITY;

#pragma unroll
    for (int fr = 0; fr < 4; ++fr)
#pragma unroll
        for (int fc = 0; fc < 4; ++fc)
#pragma unroll
            for (int r = 0; r < 4; ++r) {
                float d = anorm[fr][r] - 2.0f * acc[fr][fc][r] + bnorm[fc];
                rmin[fr][r] = fminf(rmin[fr][r], d);
                cmin[fc] = fminf(cmin[fc], d);
            }

#pragma unroll
    for (int fr = 0; fr < 4; ++fr)
#pragma unroll
        for (int r = 0; r < 4; ++r) {
#pragma unroll
            for (int off = 1; off < 16; off <<= 1)
                rmin[fr][r] = fminf(rmin[fr][r], __shfl_xor(rmin[fr][r], off));
        }
#pragma unroll
    for (int fc = 0; fc < 4; ++fc) {
#pragma unroll
        for (int off = 16; off < 64; off <<= 1)
            cmin[fc] = fminf(cmin[fc], __shfl_xor(cmin[fc], off));
    }

    if ((lane & 15) == 0) {
#pragma unroll
        for (int fr = 0; fr < 4; ++fr)
#pragma unroll
            for (int r = 0; r < 4; ++r)
                rowred[wcol * TMM + wrow * 64 + fr * 16 + rgrp + r] = rmin[fr][r];
    }
    if (lane < 16) {
#pragma unroll
        for (int fc = 0; fc < 4; ++fc)
            colred[wrow * TNN + wcol * 64 + fc * 16 + lane] = cmin[fc];
    }
    __syncthreads();
    if (tid < TMM) {
        rowpart[((size_t)(b * 4 + nt)) * NV + mt * TMM + tid] =
            fminf(rowred[tid], rowred[TMM + tid]);
    } else if (tid < TMM + TNN) {
        int c2 = tid - TMM;
        colpart[((size_t)(b * 4 + mt)) * NL + nt * TNN + c2] =
            fminf(fminf(colred[0 * TNN + c2], colred[1 * TNN + c2]),
                  fminf(colred[2 * TNN + c2], colred[3 * TNN + c2]));
    }
}

// ---------------- final reduce ----------------------------------------------
__global__ __launch_bounds__(256) void reduce2_kernel(
    const float* __restrict__ rowpart, const float* __restrict__ colpart,
    float* __restrict__ out) {
    int b = blockIdx.x;
    int tid = threadIdx.x;
    float s = 0.0f;
    for (int r = tid; r < NV; r += 256) {
        float m = INFINITY;
#pragma unroll
        for (int nt = 0; nt < 4; nt++)
            m = fminf(m, rowpart[((size_t)(b * 4 + nt)) * NV + r]);
        s += m * (1.0f / NV);
    }
    for (int c = tid; c < NL; c += 256) {
        float m = INFINITY;
#pragma unroll
        for (int mt = 0; mt < 4; mt++)
            m = fminf(m, colpart[((size_t)(b * 4 + mt)) * NL + c]);
        s += m * (1.0f / NL);
    }
    __shared__ float red[4];
#pragma unroll
    for (int off = 32; off > 0; off >>= 1) s += __shfl_down(s, off);
    if ((tid & 63) == 0) red[tid >> 6] = s;
    __syncthreads();
    if (tid == 0) out[b] = red[0] + red[1] + red[2] + red[3];
}

// ============================================================================
extern "C" void kernel_launch(void* const* d_in, const int* in_sizes, int n_in,
                              void* d_out, int out_size, void* d_ws, size_t ws_size,
                              hipStream_t stream) {
    const float* video = (const float*)d_in[0];  // [64,1024,512] fp32
    const float* lang = (const float*)d_in[1];   // [64,512,512] fp32
    float* out = (float*)d_out;                  // [64]

    float* rowpart = (float*)d_ws;                      // 64*4*1024 floats (1 MB)
    float* colpart = rowpart + (size_t)BATCH * 4 * NV;  // 64*4*512 floats (0.5 MB)

    fused_distmin_kernel<<<dim3(1024), 512, 0, stream>>>(video, lang, rowpart, colpart);
    reduce2_kernel<<<BATCH, 256, 0, stream>>>(rowpart, colpart, out);
}